// Round 6
// baseline (912.247 us; speedup 1.0000x reference)
//
#include <hip/hip_runtime.h>
#include <hip/hip_bf16.h>

// ---------------------------------------------------------------------------
// SovarielOmega fused net — round 5 (= round 3 resubmit; broker timeouts x2).
// Pipelined persistent-LSTM (counted vmcnt, gate-complete wave mapping,
// in-register gates).
// B=2048, S=8, RAW=1024, E=512, H=256, NH=8
// ---------------------------------------------------------------------------

#define ROWS   16384      // B*S
#define BATCH  2048

typedef __bf16 bf16x8 __attribute__((ext_vector_type(8)));
typedef float  f32x4  __attribute__((ext_vector_type(4)));

typedef __hip_bfloat16 bf16;

// ---- workspace layout (byte offsets) ----
#define MB(x) ((size_t)(x) << 20)
static const size_t OFF_WB    = 0;
static const size_t OFF_ABF   = MB(12);
static const size_t OFF_VBF   = MB(44);
static const size_t OFF_M1A   = MB(76);
static const size_t OFF_M1V   = MB(92);
static const size_t OFF_SEQ   = MB(108);
static const size_t OFF_PRE   = MB(124);    // bf16 (2,16384,1024) = 64 MB
static const size_t OFF_LSTM1 = MB(210);
static const size_t OFF_LSTM2 = MB(226);
static const size_t OFF_QKV   = MB(12);     // bf16 (16384,1536) (ABF/VBF dead)
static const size_t OFF_CTX   = MB(108);    // reuse SEQ
static const size_t OFF_AOUT  = MB(12);     // fp32 (16384,512) (QKV dead)
static const size_t OFF_COLSUM= MB(242);
static const size_t OFF_WTS   = MB(243);
static const size_t OFF_SUMM  = MB(244);
static const size_t OFF_WC1T  = MB(248);

// weight bf16 element offsets within OFF_WB
static const size_t WB_WA1  = 0;
static const size_t WB_WV1  = 524288;
static const size_t WB_WA2  = 1048576;
static const size_t WB_WV2  = 1179648;
static const size_t WB_WIH  = 1310720;
static const size_t WB_WHH  = 3407872;
static const size_t WB_WQKV = 4456448;
static const size_t WB_WO   = 5242880;

// ---------------------------------------------------------------------------
// batched fp32 -> bf16 convert
// ---------------------------------------------------------------------------
struct ConvJobs {
    const float* src[10];
    bf16*        dst[10];
    long long    cum[11];
};

__global__ __launch_bounds__(256) void convert_bf16(ConvJobs jobs, long long total4)
{
    for (long long g = (long long)blockIdx.x * 256 + threadIdx.x; g < total4;
         g += (long long)gridDim.x * 256) {
        int j = 0;
        while (g >= jobs.cum[j + 1]) ++j;
        const long long idx = g - jobs.cum[j];
        const float4 v = ((const float4*)jobs.src[j])[idx];
        union { ushort4 u; bf16 h[4]; } p;
        p.h[0] = __float2bfloat16(v.x);
        p.h[1] = __float2bfloat16(v.y);
        p.h[2] = __float2bfloat16(v.z);
        p.h[3] = __float2bfloat16(v.w);
        ((ushort4*)jobs.dst[j])[idx] = p.u;
    }
}

// ---------------------------------------------------------------------------
__device__ __forceinline__ void gload_lds16(const void* g, void* l)
{
    __builtin_amdgcn_global_load_lds(
        (const __attribute__((address_space(1))) unsigned int*)g,
        (__attribute__((address_space(3))) unsigned int*)l, 16, 0, 0);
}

// ---------------------------------------------------------------------------
// bf16 MFMA GEMM: C = act(A · W^T + b1 + b2 + D)   (128x128 tile, BK=32)
// ---------------------------------------------------------------------------
__global__ __launch_bounds__(256) void gemm_mfma(
    const bf16* __restrict__ A, long long sAz,
    const bf16* __restrict__ W, long long sWz,
    const float* __restrict__ b1, long long sb1,
    const float* __restrict__ b2, long long sb2,
    const bf16* __restrict__ D, long long sDz, int ldd,
    float* Cf, long long sCfz,
    bf16* Cb, long long sCbz,
    int M, int N, int K, int ldc, int coloff, int relu)
{
    const int z = blockIdx.z;
    A += (long long)z * sAz;
    W += (long long)z * sWz;
    if (b1) b1 += (long long)z * sb1;
    if (b2) b2 += (long long)z * sb2;
    if (D)  D  += (long long)z * sDz;
    if (Cf) Cf += (long long)z * sCfz;
    if (Cb) Cb += (long long)z * sCbz;

    __shared__ bf16 As[128 * 32];
    __shared__ bf16 Bs[128 * 32];

    const int tid  = threadIdx.x;
    const int wave = tid >> 6;
    const int lane = tid & 63;
    const int wm = wave >> 1;
    const int wn = wave & 1;
    const long long m0 = (long long)blockIdx.x * 128;
    const long long n0 = (long long)blockIdx.y * 128;

    const int srow = tid >> 2;
    const int scol = (tid & 3) * 8;

    f32x4 acc[4][4] = {};

    const bf16* Abase = A + (m0 + srow) * (long long)K + scol;
    const bf16* Wbase = W + (n0 + srow) * (long long)K + scol;
    const long long K64 = (long long)K * 64;

    const int lrow = (lane >> 4) * 8;
    const int frow = lane & 15;

    for (int k0 = 0; k0 < K; k0 += 32) {
        gload_lds16(Abase + k0,        As + tid * 8);
        gload_lds16(Abase + k0 + K64,  As + 2048 + tid * 8);
        gload_lds16(Wbase + k0,        Bs + tid * 8);
        gload_lds16(Wbase + k0 + K64,  Bs + 2048 + tid * 8);
        __syncthreads();

        bf16x8 af[4], bfv[4];
#pragma unroll
        for (int i = 0; i < 4; ++i)
            af[i] = *(const bf16x8*)(As + (wm * 64 + i * 16 + frow) * 32 + lrow);
#pragma unroll
        for (int j = 0; j < 4; ++j)
            bfv[j] = *(const bf16x8*)(Bs + (wn * 64 + j * 16 + frow) * 32 + lrow);
#pragma unroll
        for (int i = 0; i < 4; ++i)
#pragma unroll
            for (int j = 0; j < 4; ++j)
                acc[i][j] = __builtin_amdgcn_mfma_f32_16x16x32_bf16(af[i], bfv[j], acc[i][j], 0, 0, 0);
        __syncthreads();
    }

    const long long mwb = m0 + wm * 64;
    const long long nwb = n0 + wn * 64;
    const int rbase = (lane >> 4) * 4;
    const int lcol = lane & 15;
#pragma unroll
    for (int j = 0; j < 4; ++j) {
        const long long col = nwb + j * 16 + lcol;
        float bias = 0.f;
        if (b1) bias += b1[col];
        if (b2) bias += b2[col];
#pragma unroll
        for (int i = 0; i < 4; ++i) {
            const long long rowb = mwb + i * 16 + rbase;
#pragma unroll
            for (int r = 0; r < 4; ++r) {
                const long long row = rowb + r;
                float v = acc[i][j][r] + bias;
                if (D) v += __bfloat162float(D[row * (long long)ldd + col]);
                if (relu) v = fmaxf(v, 0.f);
                if (Cf) Cf[row * (long long)ldc + coloff + col] = v;
                if (Cb) Cb[row * (long long)ldc + coloff + col] = __float2bfloat16(v);
            }
        }
    }
}

// ---------------------------------------------------------------------------
__device__ __forceinline__ float sigf(float x) { return 1.f / (1.f + expf(-x)); }

// ---------------------------------------------------------------------------
// Pipelined persistent BiLSTM layer.
// Grid 256 x 512 (8 waves). Block owns 16 (dir,batch) rows for all 8 steps.
// Whh-dir (1024x256 bf16 = 512 KB) streamed from L2 in 8 chunks of 128 rows,
// double-buffered, 2-slots-ahead prefetch with counted vmcnt(8) (never 0).
// Wave w owns preact n-cols [w*32, w*32+32) of ALL FOUR gates -> gates are
// computed fully in-lane from MFMA accumulators (no preact LDS round-trip);
// c-state lives in VGPRs. h-tile in LDS (stride 264 -> conflict-free b128).
// ---------------------------------------------------------------------------
__global__ __launch_bounds__(512, 2) void lstm_layer(
    const bf16* __restrict__ PRE,    // (2,16384,1024) bf16, biases included
    const bf16* __restrict__ Whh,    // (2,1024,256) bf16, this layer
    bf16* __restrict__ lout)         // (16384,512) bf16: fwd 0..255, bwd 256..511
{
    __shared__ bf16 Bs[2][128 * 256];   // 2 x 64 KB chunk double-buffer
    __shared__ bf16 Hs[16 * 264];       // h tile, padded stride 264

    const int tid  = threadIdx.x;
    const int wave = tid >> 6;          // 0..7
    const int lane = tid & 63;
    const int frow = lane & 15;
    const int g8   = lane >> 4;         // 0..3

    const int R0  = blockIdx.x * 16;    // 4096 rows = 2 dirs x 2048
    const int dir = R0 >> 11;
    const int b0  = R0 & 2047;
    const bf16* Wd   = Whh + (size_t)dir * 1024 * 256;
    const bf16* PREd = PRE + (size_t)dir * 16384 * 1024;

    float cst[2][4] = {};               // c-state: 2 n-chunks x 4 rows per lane

// stage chunk c (Whh rows [c*128,+128) x K=256) into Bs[bi]; XOR source-swizzle
// (linear LDS dest + inverse-swizzled global source; reads apply same XOR)
#define STAGE(c, bi)                                                        \
    {                                                                       \
        const bf16* _src = Wd + (size_t)(c) * 128 * 256;                    \
        _Pragma("unroll")                                                   \
        for (int _q = 0; _q < 8; ++_q) {                                    \
            const int _t16 = _q * 512 + tid;                                \
            const int _row = _t16 >> 5;                                     \
            const int _cg  = (_t16 & 31) ^ (_row & 7);                      \
            gload_lds16(_src + _row * 256 + _cg * 8, &Bs[bi][_t16 * 8]);    \
        }                                                                   \
    }

    STAGE(0, 0);
    STAGE(1, 1);

    for (int t = 0; t < 8; ++t) {
        const int te = dir ? (7 - t) : t;

        // PRE gate addends for this step: 4 gates x 2 n-chunks x 4 rows
        float pv[4][2][4];
#pragma unroll
        for (int r = 0; r < 4; ++r) {
            const bf16* pr = PREd + ((size_t)(b0 + g8 * 4 + r) * 8 + te) * 1024
                             + wave * 32 + frow;
#pragma unroll
            for (int q = 0; q < 4; ++q)
#pragma unroll
                for (int nc = 0; nc < 2; ++nc)
                    pv[q][nc][r] = __bfloat162float(pr[q * 256 + nc * 16]);
        }

        f32x4 acc[4][2] = {};           // [gate][n-chunk], zero each step
        if (t > 0) {
            // A-frags: h rows 0..15 x K=256 (Hs valid: written+fenced last step)
            bf16x8 af[8];
#pragma unroll
            for (int ks = 0; ks < 8; ++ks)
                af[ks] = *(const bf16x8*)(Hs + frow * 264 + ks * 32 + g8 * 8);

#pragma unroll
            for (int c = 0; c < 8; ++c) {
                // counted wait: chunk c landed; chunk c+1's 8 loads stay in flight
                asm volatile("s_waitcnt vmcnt(8)" ::: "memory");
                __builtin_amdgcn_s_barrier();
                if ((wave >> 2) == (c & 1)) {       // waves 0-3: even chunks, 4-7: odd
                    const int rb = (wave & 3) * 32; // row base within chunk
#pragma unroll
                    for (int nc = 0; nc < 2; ++nc) {
                        const int rl = rb + nc * 16 + frow;
#pragma unroll
                        for (int ks = 0; ks < 8; ++ks) {
                            const bf16x8 bv = *(const bf16x8*)(
                                &Bs[c & 1][rl * 256 + (((ks * 4 + g8) ^ (rl & 7)) * 8)]);
                            acc[c >> 1][nc] = __builtin_amdgcn_mfma_f32_16x16x32_bf16(
                                af[ks], bv, acc[c >> 1][nc], 0, 0, 0);
                        }
                    }
                }
                asm volatile("s_waitcnt lgkmcnt(0)" ::: "memory");
                __builtin_amdgcn_s_barrier();
                // prefetch chunk c+2 into the buffer just consumed
                if (t < 7 || c < 6) STAGE((c + 2) & 7, c & 1);
            }
        }

        // gates: fully in-lane (acc is zero at t==0)
#pragma unroll
        for (int nc = 0; nc < 2; ++nc)
#pragma unroll
            for (int r = 0; r < 4; ++r) {
                const float ig = pv[0][nc][r] + acc[0][nc][r];
                const float fg = pv[1][nc][r] + acc[1][nc][r];
                const float gg = pv[2][nc][r] + acc[2][nc][r];
                const float og = pv[3][nc][r] + acc[3][nc][r];
                const float cc = sigf(fg) * cst[nc][r] + sigf(ig) * tanhf(gg);
                const float hh = sigf(og) * tanhf(cc);
                cst[nc][r] = cc;
                const int row = g8 * 4 + r;
                const int n   = wave * 32 + nc * 16 + frow;
                Hs[row * 264 + n] = __float2bfloat16(hh);
                lout[((size_t)(b0 + row) * 8 + te) * 512 + dir * 256 + n] =
                    __float2bfloat16(hh);
            }
        asm volatile("s_waitcnt lgkmcnt(0)" ::: "memory");
        __builtin_amdgcn_s_barrier();   // Hs visible to all waves for next step
    }
#undef STAGE
}

// ---------------------------------------------------------------------------
// one wave per (b, head); QKV bf16
__global__ __launch_bounds__(64) void attn_kernel(
    const bf16* __restrict__ qkv,    // (16384, 1536) bf16
    bf16* __restrict__ ctx,          // (16384, 512) bf16
    float* __restrict__ colsum)      // (2048, 8, 8)
{
    const int bh = blockIdx.x;
    const int b = bh >> 3;
    const int h = bh & 7;
    const int t = threadIdx.x;

    __shared__ float q[8][64], k[8][64], v[8][64], p[8][8];
    const bf16* base = qkv + (size_t)b * 8 * 1536 + h * 64;
#pragma unroll
    for (int s = 0; s < 8; ++s) {
        q[s][t] = __bfloat162float(base[s * 1536 + t]);
        k[s][t] = __bfloat162float(base[s * 1536 + 512 + t]);
        v[s][t] = __bfloat162float(base[s * 1536 + 1024 + t]);
    }
    __syncthreads();

    const int qi = t >> 3;
    const int kj = t & 7;
    float sc = 0.f;
#pragma unroll
    for (int d = 0; d < 64; ++d) sc += q[qi][d] * k[kj][d];
    sc *= 0.125f;

    float mx = sc;
    for (int off = 1; off < 8; off <<= 1) mx = fmaxf(mx, __shfl_xor(mx, off));
    const float e = expf(sc - mx);
    float sum = e;
    for (int off = 1; off < 8; off <<= 1) sum += __shfl_xor(sum, off);
    const float P = e / sum;
    p[qi][kj] = P;

    float cs = P;
    for (int off = 8; off < 64; off <<= 1) cs += __shfl_xor(cs, off);
    if (t < 8) colsum[(size_t)bh * 8 + t] = cs;
    __syncthreads();

    bf16* cb = ctx + ((size_t)b * 8 + qi) * 512 + h * 64;
#pragma unroll
    for (int j = 0; j < 8; ++j) {
        const int d = (t & 7) + 8 * j;
        float o = 0.f;
#pragma unroll
        for (int kk = 0; kk < 8; ++kk) o += p[qi][kk] * v[kk][d];
        cb[d] = __float2bfloat16(o);
    }
}

__global__ __launch_bounds__(64) void weights_kernel(
    const float* __restrict__ colsum, float* __restrict__ wts)
{
    const int t = threadIdx.x;
    const int b = blockIdx.x * 8 + (t >> 3);
    const int kk = t & 7;
    const float* cs = colsum + (size_t)b * 64;
    float s = 0.f;
#pragma unroll
    for (int h = 0; h < 8; ++h) s += cs[h * 8 + kk];
    s *= (1.f / 64.f);
    float mx = s;
    for (int off = 1; off < 8; off <<= 1) mx = fmaxf(mx, __shfl_xor(mx, off));
    const float e = expf(s - mx);
    float sum = e;
    for (int off = 1; off < 8; off <<= 1) sum += __shfl_xor(sum, off);
    wts[(size_t)b * 8 + kk] = e / sum;
}

__global__ __launch_bounds__(256) void summary_kernel(
    const float* __restrict__ aout, const float* __restrict__ wts,
    float* __restrict__ summ)
{
    const int gid = blockIdx.x * 256 + threadIdx.x;
    const int b = gid >> 9;
    const int e = gid & 511;
    const float* ab = aout + (size_t)b * 8 * 512 + e;
    const float* wb = wts + (size_t)b * 8;
    float s = 0.f;
#pragma unroll
    for (int t = 0; t < 8; ++t) s += ab[t * 512] * wb[t];
    summ[gid] = s;
}

__global__ __launch_bounds__(256) void transpose_wc1(
    const float* __restrict__ Wc1, float* __restrict__ Wc1T)
{
    const int gid = blockIdx.x * 256 + threadIdx.x;   // 256*513
    const int j = gid / 513;
    const int e = gid % 513;
    Wc1T[(size_t)e * 256 + j] = Wc1[gid];
}

__global__ __launch_bounds__(256) void coherence_kernel(
    const float* __restrict__ summ, const float* __restrict__ Wc1T,
    const float* __restrict__ bc1, const float* __restrict__ Wc2,
    const float* __restrict__ bc2, float* __restrict__ out)
{
    const int b = blockIdx.x;
    const int j = threadIdx.x;
    __shared__ float s[512];
    __shared__ float red[4];
    s[j]       = summ[(size_t)b * 512 + j];
    s[j + 256] = summ[(size_t)b * 512 + 256 + j];
    __syncthreads();

    float hj = bc1[j];
    for (int e = 0; e < 512; ++e) hj += s[e] * Wc1T[(size_t)e * 256 + j];
    hj = fmaxf(hj, 0.f);
    float val = hj * Wc2[j];
    for (int off = 1; off < 64; off <<= 1) val += __shfl_xor(val, off);
    if ((j & 63) == 0) red[j >> 6] = val;
    __syncthreads();
    if (j == 0) {
        const float tot = red[0] + red[1] + red[2] + red[3] + bc2[0];
        const float c = 1.f / (1.f + expf(-tot));
        out[b] = fminf(c, 0.9998f);
    }
}

// ---------------------------------------------------------------------------
extern "C" void kernel_launch(void* const* d_in, const int* in_sizes, int n_in,
                              void* d_out, int out_size, void* d_ws, size_t ws_size,
                              hipStream_t stream)
{
    (void)in_sizes; (void)n_in; (void)out_size; (void)ws_size;

    const float* audio  = (const float*)d_in[0];
    const float* visual = (const float*)d_in[1];
    const float* Wa1 = (const float*)d_in[2];  const float* ba1 = (const float*)d_in[3];
    const float* Wa2 = (const float*)d_in[4];  const float* ba2 = (const float*)d_in[5];
    const float* Wv1 = (const float*)d_in[6];  const float* bv1 = (const float*)d_in[7];
    const float* Wv2 = (const float*)d_in[8];  const float* bv2 = (const float*)d_in[9];
    const float* Wih = (const float*)d_in[10]; const float* Whh = (const float*)d_in[11];
    const float* bih = (const float*)d_in[12]; const float* bhh = (const float*)d_in[13];
    const float* Wqkv = (const float*)d_in[14]; const float* bqkv = (const float*)d_in[15];
    const float* Wo  = (const float*)d_in[16]; const float* bo  = (const float*)d_in[17];
    const float* Wc1 = (const float*)d_in[18]; const float* bc1 = (const float*)d_in[19];
    const float* Wc2 = (const float*)d_in[20]; const float* bc2 = (const float*)d_in[21];

    char* wsb = (char*)d_ws;
    float* out = (float*)d_out;

    bf16* WB    = (bf16*)(wsb + OFF_WB);
    bf16* ABF   = (bf16*)(wsb + OFF_ABF);
    bf16* VBF   = (bf16*)(wsb + OFF_VBF);
    bf16* M1A   = (bf16*)(wsb + OFF_M1A);
    bf16* M1V   = (bf16*)(wsb + OFF_M1V);
    bf16* SEQ   = (bf16*)(wsb + OFF_SEQ);
    bf16* PRE   = (bf16*)(wsb + OFF_PRE);
    bf16* LSTM1 = (bf16*)(wsb + OFF_LSTM1);
    bf16* LSTM2 = (bf16*)(wsb + OFF_LSTM2);
    bf16* QKVB  = (bf16*)(wsb + OFF_QKV);
    bf16* CTX   = (bf16*)(wsb + OFF_CTX);
    float* AOUT = (float*)(wsb + OFF_AOUT);
    float* COLSUM = (float*)(wsb + OFF_COLSUM);
    float* WTS  = (float*)(wsb + OFF_WTS);
    float* SUMM = (float*)(wsb + OFF_SUMM);
    float* WC1T = (float*)(wsb + OFF_WC1T);

    bf16* Wa1b = WB + WB_WA1;  bf16* Wv1b = WB + WB_WV1;
    bf16* Wa2b = WB + WB_WA2;  bf16* Wv2b = WB + WB_WV2;
    bf16* Wihb = WB + WB_WIH;  bf16* Whhb = WB + WB_WHH;
    bf16* Wqkvb = WB + WB_WQKV; bf16* Wob = WB + WB_WO;

    // --- batched convert fp32 -> bf16 ---
    {
        ConvJobs cj;
        const float* srcs[10] = {audio, visual, Wa1, Wa2, Wv1, Wv2, Wih, Whh, Wqkv, Wo};
        bf16* dsts[10] = {ABF, VBF, Wa1b, Wa2b, Wv1b, Wv2b, Wihb, Whhb, Wqkvb, Wob};
        const long long cnt4[10] = {4194304, 4194304, 131072, 32768, 131072, 32768,
                                    524288, 262144, 196608, 65536};
        long long cum = 0;
        for (int i = 0; i < 10; ++i) {
            cj.src[i] = srcs[i]; cj.dst[i] = dsts[i];
            cj.cum[i] = cum; cum += cnt4[i];
        }
        cj.cum[10] = cum;
        hipLaunchKernelGGL(convert_bf16, dim3(2048), dim3(256), 0, stream, cj, cum);
    }

    auto gemm = [&](const bf16* A, long long sAz, const bf16* W, long long sWz,
                    const float* b1, long long sb1, const float* b2, long long sb2,
                    const bf16* D, long long sDz, int ldd,
                    float* Cf, long long sCfz, bf16* Cb, long long sCbz,
                    int M, int N, int K, int ldc, int coloff, int relu, int nz) {
        dim3 grid(M / 128, N / 128, nz);
        hipLaunchKernelGGL(gemm_mfma, grid, dim3(256), 0, stream,
                           A, sAz, W, sWz, b1, sb1, b2, sb2, D, sDz, ldd,
                           Cf, sCfz, Cb, sCbz, M, N, K, ldc, coloff, relu);
    };

    // --- modality MLPs ---
    gemm(ABF, 0, Wa1b, 0, ba1, 0, nullptr, 0, nullptr, 0, 0,
         nullptr, 0, M1A, 0, ROWS, 512, 1024, 512, 0, 1, 1);
    gemm(VBF, 0, Wv1b, 0, bv1, 0, nullptr, 0, nullptr, 0, 0,
         nullptr, 0, M1V, 0, ROWS, 512, 1024, 512, 0, 1, 1);
    gemm(M1A, 0, Wa2b, 0, ba2, 0, nullptr, 0, nullptr, 0, 0,
         nullptr, 0, SEQ, 0, ROWS, 256, 512, 512, 0, 0, 1);
    gemm(M1V, 0, Wv2b, 0, bv2, 0, nullptr, 0, nullptr, 0, 0,
         nullptr, 0, SEQ, 0, ROWS, 256, 512, 512, 256, 0, 1);

    // --- BiLSTM, 2 layers ---
    for (int l = 0; l < 2; ++l) {
        const bf16* xin = (l == 0) ? SEQ : LSTM1;
        bf16* lout      = (l == 0) ? LSTM1 : LSTM2;
        const bf16* Wih_l = Wihb + (size_t)l * 2 * 1024 * 512;
        const bf16* Whh_l = Whhb + (size_t)l * 2 * 1024 * 256;
        const float* bih_l = bih + (size_t)l * 2 * 1024;
        const float* bhh_l = bhh + (size_t)l * 2 * 1024;

        // input projection, both dirs via z -> PRE bf16 (incl. both biases)
        gemm(xin, 0, Wih_l, 1024LL * 512, bih_l, 1024, bhh_l, 1024,
             nullptr, 0, 0, nullptr, 0, PRE, 16384LL * 1024,
             ROWS, 1024, 512, 1024, 0, 0, 2);

        // full recurrence in one persistent pipelined kernel
        hipLaunchKernelGGL(lstm_layer, dim3(256), dim3(512), 0, stream,
                           PRE, Whh_l, lout);
    }

    // --- MHA ---
    gemm(LSTM2, 0, Wqkvb, 0, bqkv, 0, nullptr, 0, nullptr, 0, 0,
         nullptr, 0, QKVB, 0, ROWS, 1536, 512, 1536, 0, 0, 1);
    hipLaunchKernelGGL(attn_kernel, dim3(BATCH * 8), dim3(64), 0, stream, QKVB, CTX, COLSUM);
    hipLaunchKernelGGL(weights_kernel, dim3(BATCH / 8), dim3(64), 0, stream, COLSUM, WTS);
    gemm(CTX, 0, Wob, 0, bo, 0, nullptr, 0, nullptr, 0, 0,
         AOUT, 0, nullptr, 0, ROWS, 512, 512, 512, 0, 0, 1);

    // --- pooling + head ---
    hipLaunchKernelGGL(summary_kernel, dim3(BATCH * 512 / 256), dim3(256), 0, stream,
                       AOUT, WTS, SUMM);
    hipLaunchKernelGGL(transpose_wc1, dim3(513), dim3(256), 0, stream, Wc1, WC1T);
    hipLaunchKernelGGL(coherence_kernel, dim3(BATCH), dim3(256), 0, stream,
                       SUMM, WC1T, bc1, Wc2, bc2, out);
}

// Round 7
// 796.630 us; speedup vs baseline: 1.1451x; 1.1451x over previous
//
#include <hip/hip_runtime.h>
#include <hip/hip_bf16.h>

// ---------------------------------------------------------------------------
// SovarielOmega fused net — round 6: revert LSTM to round-2 coalesced layout
// + double-buffered issue-early Whh stream (m97-style overlap, plain barriers).
// B=2048, S=8, RAW=1024, E=512, H=256, NH=8
// ---------------------------------------------------------------------------

#define ROWS   16384      // B*S
#define BATCH  2048

typedef __bf16 bf16x8 __attribute__((ext_vector_type(8)));
typedef float  f32x4  __attribute__((ext_vector_type(4)));

typedef __hip_bfloat16 bf16;

// ---- workspace layout (byte offsets) ----
#define MB(x) ((size_t)(x) << 20)
static const size_t OFF_WB    = 0;
static const size_t OFF_ABF   = MB(12);
static const size_t OFF_VBF   = MB(44);
static const size_t OFF_M1A   = MB(76);
static const size_t OFF_M1V   = MB(92);
static const size_t OFF_SEQ   = MB(108);
static const size_t OFF_PRE   = MB(124);    // bf16 (2,16384,1024) = 64 MB
static const size_t OFF_LSTM1 = MB(210);
static const size_t OFF_LSTM2 = MB(226);
static const size_t OFF_QKV   = MB(12);     // bf16 (16384,1536) (ABF/VBF dead)
static const size_t OFF_CTX   = MB(108);    // reuse SEQ
static const size_t OFF_AOUT  = MB(12);     // fp32 (16384,512) (QKV dead)
static const size_t OFF_COLSUM= MB(242);
static const size_t OFF_WTS   = MB(243);
static const size_t OFF_SUMM  = MB(244);
static const size_t OFF_WC1T  = MB(248);

// weight bf16 element offsets within OFF_WB
static const size_t WB_WA1  = 0;
static const size_t WB_WV1  = 524288;
static const size_t WB_WA2  = 1048576;
static const size_t WB_WV2  = 1179648;
static const size_t WB_WIH  = 1310720;
static const size_t WB_WHH  = 3407872;
static const size_t WB_WQKV = 4456448;
static const size_t WB_WO   = 5242880;

// ---------------------------------------------------------------------------
// batched fp32 -> bf16 convert
// ---------------------------------------------------------------------------
struct ConvJobs {
    const float* src[10];
    bf16*        dst[10];
    long long    cum[11];
};

__global__ __launch_bounds__(256) void convert_bf16(ConvJobs jobs, long long total4)
{
    for (long long g = (long long)blockIdx.x * 256 + threadIdx.x; g < total4;
         g += (long long)gridDim.x * 256) {
        int j = 0;
        while (g >= jobs.cum[j + 1]) ++j;
        const long long idx = g - jobs.cum[j];
        const float4 v = ((const float4*)jobs.src[j])[idx];
        union { ushort4 u; bf16 h[4]; } p;
        p.h[0] = __float2bfloat16(v.x);
        p.h[1] = __float2bfloat16(v.y);
        p.h[2] = __float2bfloat16(v.z);
        p.h[3] = __float2bfloat16(v.w);
        ((ushort4*)jobs.dst[j])[idx] = p.u;
    }
}

// ---------------------------------------------------------------------------
__device__ __forceinline__ void gload_lds16(const void* g, void* l)
{
    __builtin_amdgcn_global_load_lds(
        (const __attribute__((address_space(1))) unsigned int*)g,
        (__attribute__((address_space(3))) unsigned int*)l, 16, 0, 0);
}

// ---------------------------------------------------------------------------
// bf16 MFMA GEMM: C = act(A · W^T + b1 + b2 + D)   (128x128 tile, BK=32)
// ---------------------------------------------------------------------------
__global__ __launch_bounds__(256) void gemm_mfma(
    const bf16* __restrict__ A, long long sAz,
    const bf16* __restrict__ W, long long sWz,
    const float* __restrict__ b1, long long sb1,
    const float* __restrict__ b2, long long sb2,
    const bf16* __restrict__ D, long long sDz, int ldd,
    float* Cf, long long sCfz,
    bf16* Cb, long long sCbz,
    int M, int N, int K, int ldc, int coloff, int relu)
{
    const int z = blockIdx.z;
    A += (long long)z * sAz;
    W += (long long)z * sWz;
    if (b1) b1 += (long long)z * sb1;
    if (b2) b2 += (long long)z * sb2;
    if (D)  D  += (long long)z * sDz;
    if (Cf) Cf += (long long)z * sCfz;
    if (Cb) Cb += (long long)z * sCbz;

    __shared__ bf16 As[128 * 32];
    __shared__ bf16 Bs[128 * 32];

    const int tid  = threadIdx.x;
    const int wave = tid >> 6;
    const int lane = tid & 63;
    const int wm = wave >> 1;
    const int wn = wave & 1;
    const long long m0 = (long long)blockIdx.x * 128;
    const long long n0 = (long long)blockIdx.y * 128;

    const int srow = tid >> 2;
    const int scol = (tid & 3) * 8;

    f32x4 acc[4][4] = {};

    const bf16* Abase = A + (m0 + srow) * (long long)K + scol;
    const bf16* Wbase = W + (n0 + srow) * (long long)K + scol;
    const long long K64 = (long long)K * 64;

    const int lrow = (lane >> 4) * 8;
    const int frow = lane & 15;

    for (int k0 = 0; k0 < K; k0 += 32) {
        gload_lds16(Abase + k0,        As + tid * 8);
        gload_lds16(Abase + k0 + K64,  As + 2048 + tid * 8);
        gload_lds16(Wbase + k0,        Bs + tid * 8);
        gload_lds16(Wbase + k0 + K64,  Bs + 2048 + tid * 8);
        __syncthreads();

        bf16x8 af[4], bfv[4];
#pragma unroll
        for (int i = 0; i < 4; ++i)
            af[i] = *(const bf16x8*)(As + (wm * 64 + i * 16 + frow) * 32 + lrow);
#pragma unroll
        for (int j = 0; j < 4; ++j)
            bfv[j] = *(const bf16x8*)(Bs + (wn * 64 + j * 16 + frow) * 32 + lrow);
#pragma unroll
        for (int i = 0; i < 4; ++i)
#pragma unroll
            for (int j = 0; j < 4; ++j)
                acc[i][j] = __builtin_amdgcn_mfma_f32_16x16x32_bf16(af[i], bfv[j], acc[i][j], 0, 0, 0);
        __syncthreads();
    }

    const long long mwb = m0 + wm * 64;
    const long long nwb = n0 + wn * 64;
    const int rbase = (lane >> 4) * 4;
    const int lcol = lane & 15;
#pragma unroll
    for (int j = 0; j < 4; ++j) {
        const long long col = nwb + j * 16 + lcol;
        float bias = 0.f;
        if (b1) bias += b1[col];
        if (b2) bias += b2[col];
#pragma unroll
        for (int i = 0; i < 4; ++i) {
            const long long rowb = mwb + i * 16 + rbase;
#pragma unroll
            for (int r = 0; r < 4; ++r) {
                const long long row = rowb + r;
                float v = acc[i][j][r] + bias;
                if (D) v += __bfloat162float(D[row * (long long)ldd + col]);
                if (relu) v = fmaxf(v, 0.f);
                if (Cf) Cf[row * (long long)ldc + coloff + col] = v;
                if (Cb) Cb[row * (long long)ldc + coloff + col] = __float2bfloat16(v);
            }
        }
    }
}

// ---------------------------------------------------------------------------
__device__ __forceinline__ float sigf(float x) { return 1.f / (1.f + expf(-x)); }

// ---------------------------------------------------------------------------
// Persistent BiLSTM layer, round-2 layout + issue-early double buffer.
// Grid 256 x 512 (8 waves). Block owns 16 (dir,batch) rows for all 8 steps.
// Per step t>0: 8 chunks of Whh (128 rows x K=256 = 64 KB) streamed through a
// 2x64 KB LDS double buffer; STAGE(c+1) issued BEFORE MFMA(c) so the load
// latency hides under ds_read+MFMA; plain __syncthreads() per chunk.
// preact fp32[16][1024] aliases buffer 0 (all MFMA reads done by then).
// Gates phase: round-2 coalesced mapping (n = tid&255 contiguous).
// Chunk-0 prefetch for step t+1 overlaps the gates phase.
// ---------------------------------------------------------------------------
__global__ __launch_bounds__(512) void lstm_layer(
    const bf16* __restrict__ PRE,    // (2,16384,1024) bf16, biases included
    const bf16* __restrict__ Whh,    // (2,1024,256) bf16, this layer
    bf16* __restrict__ lout)         // (16384,512) bf16: fwd 0..255, bwd 256..511
{
    __shared__ bf16 Bs[2][128 * 256];   // 2 x 64 KB chunk double-buffer
    __shared__ bf16 Hs[16 * 264];       // h tile, padded stride 264
    float* preact = (float*)&Bs[0][0];  // fp32[16][1024] alias, used after MFMA

    const int tid  = threadIdx.x;
    const int wave = tid >> 6;          // 0..7
    const int lane = tid & 63;
    const int frow = lane & 15;
    const int g8   = lane >> 4;         // 0..3
    const int rbase = g8 * 4;

    const int R0  = blockIdx.x * 16;    // 4096 rows = 2 dirs x 2048
    const int dir = R0 >> 11;
    const int b0  = R0 & 2047;
    const bf16* Wd   = Whh + (size_t)dir * 1024 * 256;
    const bf16* PREd = PRE + (size_t)dir * 16384 * 1024;

    // gates-phase mapping: n = tid&255, rows i*2 + (tid>>8)
    const int gn = tid & 255;
    const int rh = tid >> 8;            // 0/1

    float c_state[8];
#pragma unroll
    for (int i = 0; i < 8; ++i) c_state[i] = 0.f;

// stage chunk c (Whh rows [c*128,+128) x K=256) into Bs[bi]; XOR source-swizzle
// (linear LDS dest + inverse-swizzled global source; reads apply same XOR)
#define STAGE(c, bi)                                                        \
    {                                                                       \
        const bf16* _src = Wd + (size_t)(c) * 128 * 256;                    \
        _Pragma("unroll")                                                   \
        for (int _q = 0; _q < 8; ++_q) {                                    \
            const int _t16 = _q * 512 + tid;                                \
            const int _row = _t16 >> 5;                                     \
            const int _cg  = (_t16 & 31) ^ (_row & 7);                      \
            gload_lds16(_src + _row * 256 + _cg * 8, &Bs[bi][_t16 * 8]);    \
        }                                                                   \
    }

    for (int t = 0; t < 8; ++t) {
        if (t > 0) {
            // A-frags: h rows 0..15 x K=256 (Hs written + barrier'd last step)
            bf16x8 af[8];
#pragma unroll
            for (int ks = 0; ks < 8; ++ks)
                af[ks] = *(const bf16x8*)(Hs + frow * 264 + ks * 32 + g8 * 8);
            __syncthreads();                // drains chunk-0 prefetch (vmcnt 0)

            f32x4 acc[8] = {};
            const int lr = wave * 16 + frow;    // this wave's B rows in chunk
#pragma unroll
            for (int c = 0; c < 8; ++c) {
                if (c < 7) STAGE(c + 1, (c + 1) & 1);   // issue-early prefetch
#pragma unroll
                for (int ks = 0; ks < 8; ++ks) {
                    const bf16x8 bv = *(const bf16x8*)(
                        &Bs[c & 1][lr * 256 + (((ks * 4 + g8) ^ (lr & 7)) * 8)]);
                    acc[c] = __builtin_amdgcn_mfma_f32_16x16x32_bf16(
                        af[ks], bv, acc[c], 0, 0, 0);
                }
                __syncthreads();            // buf[c&1] reads done; drains STAGE(c+1)
            }

            // preact epilogue into aliased buffer 0
#pragma unroll
            for (int nb = 0; nb < 8; ++nb) {
                const int col = nb * 128 + wave * 16 + frow;
#pragma unroll
                for (int r = 0; r < 4; ++r)
                    preact[(rbase + r) * 1024 + col] = acc[nb][r];
            }
            __syncthreads();
        }

        // gates phase (coalesced: 256 consecutive cols per row-half)
        const int te = dir ? (7 - t) : t;
#pragma unroll
        for (int i = 0; i < 8; ++i) {
            const int row = i * 2 + rh;
            const int b = b0 + row;
            const bf16* pr = PREd + ((size_t)b * 8 + te) * 1024;
            float ig = __bfloat162float(pr[gn]);
            float fg = __bfloat162float(pr[gn + 256]);
            float gg = __bfloat162float(pr[gn + 512]);
            float og = __bfloat162float(pr[gn + 768]);
            if (t > 0) {
                ig += preact[row * 1024 + gn];
                fg += preact[row * 1024 + gn + 256];
                gg += preact[row * 1024 + gn + 512];
                og += preact[row * 1024 + gn + 768];
            }
            const float cc = sigf(fg) * c_state[i] + sigf(ig) * tanhf(gg);
            const float hh = sigf(og) * tanhf(cc);
            c_state[i] = cc;
            Hs[row * 264 + gn] = __float2bfloat16(hh);
            lout[((size_t)b * 8 + te) * 512 + dir * 256 + gn] = __float2bfloat16(hh);
        }
        __syncthreads();                    // Hs + preact reads done
        if (t < 7) STAGE(0, 0);             // chunk-0 prefetch for next step
    }
#undef STAGE
}

// ---------------------------------------------------------------------------
// one wave per (b, head); QKV bf16
__global__ __launch_bounds__(64) void attn_kernel(
    const bf16* __restrict__ qkv,    // (16384, 1536) bf16
    bf16* __restrict__ ctx,          // (16384, 512) bf16
    float* __restrict__ colsum)      // (2048, 8, 8)
{
    const int bh = blockIdx.x;
    const int b = bh >> 3;
    const int h = bh & 7;
    const int t = threadIdx.x;

    __shared__ float q[8][64], k[8][64], v[8][64], p[8][8];
    const bf16* base = qkv + (size_t)b * 8 * 1536 + h * 64;
#pragma unroll
    for (int s = 0; s < 8; ++s) {
        q[s][t] = __bfloat162float(base[s * 1536 + t]);
        k[s][t] = __bfloat162float(base[s * 1536 + 512 + t]);
        v[s][t] = __bfloat162float(base[s * 1536 + 1024 + t]);
    }
    __syncthreads();

    const int qi = t >> 3;
    const int kj = t & 7;
    float sc = 0.f;
#pragma unroll
    for (int d = 0; d < 64; ++d) sc += q[qi][d] * k[kj][d];
    sc *= 0.125f;

    float mx = sc;
    for (int off = 1; off < 8; off <<= 1) mx = fmaxf(mx, __shfl_xor(mx, off));
    const float e = expf(sc - mx);
    float sum = e;
    for (int off = 1; off < 8; off <<= 1) sum += __shfl_xor(sum, off);
    const float P = e / sum;
    p[qi][kj] = P;

    float cs = P;
    for (int off = 8; off < 64; off <<= 1) cs += __shfl_xor(cs, off);
    if (t < 8) colsum[(size_t)bh * 8 + t] = cs;
    __syncthreads();

    bf16* cb = ctx + ((size_t)b * 8 + qi) * 512 + h * 64;
#pragma unroll
    for (int j = 0; j < 8; ++j) {
        const int d = (t & 7) + 8 * j;
        float o = 0.f;
#pragma unroll
        for (int kk = 0; kk < 8; ++kk) o += p[qi][kk] * v[kk][d];
        cb[d] = __float2bfloat16(o);
    }
}

__global__ __launch_bounds__(64) void weights_kernel(
    const float* __restrict__ colsum, float* __restrict__ wts)
{
    const int t = threadIdx.x;
    const int b = blockIdx.x * 8 + (t >> 3);
    const int kk = t & 7;
    const float* cs = colsum + (size_t)b * 64;
    float s = 0.f;
#pragma unroll
    for (int h = 0; h < 8; ++h) s += cs[h * 8 + kk];
    s *= (1.f / 64.f);
    float mx = s;
    for (int off = 1; off < 8; off <<= 1) mx = fmaxf(mx, __shfl_xor(mx, off));
    const float e = expf(s - mx);
    float sum = e;
    for (int off = 1; off < 8; off <<= 1) sum += __shfl_xor(sum, off);
    wts[(size_t)b * 8 + kk] = e / sum;
}

__global__ __launch_bounds__(256) void summary_kernel(
    const float* __restrict__ aout, const float* __restrict__ wts,
    float* __restrict__ summ)
{
    const int gid = blockIdx.x * 256 + threadIdx.x;
    const int b = gid >> 9;
    const int e = gid & 511;
    const float* ab = aout + (size_t)b * 8 * 512 + e;
    const float* wb = wts + (size_t)b * 8;
    float s = 0.f;
#pragma unroll
    for (int t = 0; t < 8; ++t) s += ab[t * 512] * wb[t];
    summ[gid] = s;
}

__global__ __launch_bounds__(256) void transpose_wc1(
    const float* __restrict__ Wc1, float* __restrict__ Wc1T)
{
    const int gid = blockIdx.x * 256 + threadIdx.x;   // 256*513
    const int j = gid / 513;
    const int e = gid % 513;
    Wc1T[(size_t)e * 256 + j] = Wc1[gid];
}

__global__ __launch_bounds__(256) void coherence_kernel(
    const float* __restrict__ summ, const float* __restrict__ Wc1T,
    const float* __restrict__ bc1, const float* __restrict__ Wc2,
    const float* __restrict__ bc2, float* __restrict__ out)
{
    const int b = blockIdx.x;
    const int j = threadIdx.x;
    __shared__ float s[512];
    __shared__ float red[4];
    s[j]       = summ[(size_t)b * 512 + j];
    s[j + 256] = summ[(size_t)b * 512 + 256 + j];
    __syncthreads();

    float hj = bc1[j];
    for (int e = 0; e < 512; ++e) hj += s[e] * Wc1T[(size_t)e * 256 + j];
    hj = fmaxf(hj, 0.f);
    float val = hj * Wc2[j];
    for (int off = 1; off < 64; off <<= 1) val += __shfl_xor(val, off);
    if ((j & 63) == 0) red[j >> 6] = val;
    __syncthreads();
    if (j == 0) {
        const float tot = red[0] + red[1] + red[2] + red[3] + bc2[0];
        const float c = 1.f / (1.f + expf(-tot));
        out[b] = fminf(c, 0.9998f);
    }
}

// ---------------------------------------------------------------------------
extern "C" void kernel_launch(void* const* d_in, const int* in_sizes, int n_in,
                              void* d_out, int out_size, void* d_ws, size_t ws_size,
                              hipStream_t stream)
{
    (void)in_sizes; (void)n_in; (void)out_size; (void)ws_size;

    const float* audio  = (const float*)d_in[0];
    const float* visual = (const float*)d_in[1];
    const float* Wa1 = (const float*)d_in[2];  const float* ba1 = (const float*)d_in[3];
    const float* Wa2 = (const float*)d_in[4];  const float* ba2 = (const float*)d_in[5];
    const float* Wv1 = (const float*)d_in[6];  const float* bv1 = (const float*)d_in[7];
    const float* Wv2 = (const float*)d_in[8];  const float* bv2 = (const float*)d_in[9];
    const float* Wih = (const float*)d_in[10]; const float* Whh = (const float*)d_in[11];
    const float* bih = (const float*)d_in[12]; const float* bhh = (const float*)d_in[13];
    const float* Wqkv = (const float*)d_in[14]; const float* bqkv = (const float*)d_in[15];
    const float* Wo  = (const float*)d_in[16]; const float* bo  = (const float*)d_in[17];
    const float* Wc1 = (const float*)d_in[18]; const float* bc1 = (const float*)d_in[19];
    const float* Wc2 = (const float*)d_in[20]; const float* bc2 = (const float*)d_in[21];

    char* wsb = (char*)d_ws;
    float* out = (float*)d_out;

    bf16* WB    = (bf16*)(wsb + OFF_WB);
    bf16* ABF   = (bf16*)(wsb + OFF_ABF);
    bf16* VBF   = (bf16*)(wsb + OFF_VBF);
    bf16* M1A   = (bf16*)(wsb + OFF_M1A);
    bf16* M1V   = (bf16*)(wsb + OFF_M1V);
    bf16* SEQ   = (bf16*)(wsb + OFF_SEQ);
    bf16* PRE   = (bf16*)(wsb + OFF_PRE);
    bf16* LSTM1 = (bf16*)(wsb + OFF_LSTM1);
    bf16* LSTM2 = (bf16*)(wsb + OFF_LSTM2);
    bf16* QKVB  = (bf16*)(wsb + OFF_QKV);
    bf16* CTX   = (bf16*)(wsb + OFF_CTX);
    float* AOUT = (float*)(wsb + OFF_AOUT);
    float* COLSUM = (float*)(wsb + OFF_COLSUM);
    float* WTS  = (float*)(wsb + OFF_WTS);
    float* SUMM = (float*)(wsb + OFF_SUMM);
    float* WC1T = (float*)(wsb + OFF_WC1T);

    bf16* Wa1b = WB + WB_WA1;  bf16* Wv1b = WB + WB_WV1;
    bf16* Wa2b = WB + WB_WA2;  bf16* Wv2b = WB + WB_WV2;
    bf16* Wihb = WB + WB_WIH;  bf16* Whhb = WB + WB_WHH;
    bf16* Wqkvb = WB + WB_WQKV; bf16* Wob = WB + WB_WO;

    // --- batched convert fp32 -> bf16 ---
    {
        ConvJobs cj;
        const float* srcs[10] = {audio, visual, Wa1, Wa2, Wv1, Wv2, Wih, Whh, Wqkv, Wo};
        bf16* dsts[10] = {ABF, VBF, Wa1b, Wa2b, Wv1b, Wv2b, Wihb, Whhb, Wqkvb, Wob};
        const long long cnt4[10] = {4194304, 4194304, 131072, 32768, 131072, 32768,
                                    524288, 262144, 196608, 65536};
        long long cum = 0;
        for (int i = 0; i < 10; ++i) {
            cj.src[i] = srcs[i]; cj.dst[i] = dsts[i];
            cj.cum[i] = cum; cum += cnt4[i];
        }
        cj.cum[10] = cum;
        hipLaunchKernelGGL(convert_bf16, dim3(2048), dim3(256), 0, stream, cj, cum);
    }

    auto gemm = [&](const bf16* A, long long sAz, const bf16* W, long long sWz,
                    const float* b1, long long sb1, const float* b2, long long sb2,
                    const bf16* D, long long sDz, int ldd,
                    float* Cf, long long sCfz, bf16* Cb, long long sCbz,
                    int M, int N, int K, int ldc, int coloff, int relu, int nz) {
        dim3 grid(M / 128, N / 128, nz);
        hipLaunchKernelGGL(gemm_mfma, grid, dim3(256), 0, stream,
                           A, sAz, W, sWz, b1, sb1, b2, sb2, D, sDz, ldd,
                           Cf, sCfz, Cb, sCbz, M, N, K, ldc, coloff, relu);
    };

    // --- modality MLPs ---
    gemm(ABF, 0, Wa1b, 0, ba1, 0, nullptr, 0, nullptr, 0, 0,
         nullptr, 0, M1A, 0, ROWS, 512, 1024, 512, 0, 1, 1);
    gemm(VBF, 0, Wv1b, 0, bv1, 0, nullptr, 0, nullptr, 0, 0,
         nullptr, 0, M1V, 0, ROWS, 512, 1024, 512, 0, 1, 1);
    gemm(M1A, 0, Wa2b, 0, ba2, 0, nullptr, 0, nullptr, 0, 0,
         nullptr, 0, SEQ, 0, ROWS, 256, 512, 512, 0, 0, 1);
    gemm(M1V, 0, Wv2b, 0, bv2, 0, nullptr, 0, nullptr, 0, 0,
         nullptr, 0, SEQ, 0, ROWS, 256, 512, 512, 256, 0, 1);

    // --- BiLSTM, 2 layers ---
    for (int l = 0; l < 2; ++l) {
        const bf16* xin = (l == 0) ? SEQ : LSTM1;
        bf16* lout      = (l == 0) ? LSTM1 : LSTM2;
        const bf16* Wih_l = Wihb + (size_t)l * 2 * 1024 * 512;
        const bf16* Whh_l = Whhb + (size_t)l * 2 * 1024 * 256;
        const float* bih_l = bih + (size_t)l * 2 * 1024;
        const float* bhh_l = bhh + (size_t)l * 2 * 1024;

        // input projection, both dirs via z -> PRE bf16 (incl. both biases)
        gemm(xin, 0, Wih_l, 1024LL * 512, bih_l, 1024, bhh_l, 1024,
             nullptr, 0, 0, nullptr, 0, PRE, 16384LL * 1024,
             ROWS, 1024, 512, 1024, 0, 0, 2);

        // full recurrence in one persistent kernel
        hipLaunchKernelGGL(lstm_layer, dim3(256), dim3(512), 0, stream,
                           PRE, Whh_l, lout);
    }

    // --- MHA ---
    gemm(LSTM2, 0, Wqkvb, 0, bqkv, 0, nullptr, 0, nullptr, 0, 0,
         nullptr, 0, QKVB, 0, ROWS, 1536, 512, 1536, 0, 0, 1);
    hipLaunchKernelGGL(attn_kernel, dim3(BATCH * 8), dim3(64), 0, stream, QKVB, CTX, COLSUM);
    hipLaunchKernelGGL(weights_kernel, dim3(BATCH / 8), dim3(64), 0, stream, COLSUM, WTS);
    gemm(CTX, 0, Wob, 0, bo, 0, nullptr, 0, nullptr, 0, 0,
         AOUT, 0, nullptr, 0, ROWS, 512, 512, 512, 0, 0, 1);

    // --- pooling + head ---
    hipLaunchKernelGGL(summary_kernel, dim3(BATCH * 512 / 256), dim3(256), 0, stream,
                       AOUT, WTS, SUMM);
    hipLaunchKernelGGL(transpose_wc1, dim3(513), dim3(256), 0, stream, Wc1, WC1T);
    hipLaunchKernelGGL(coherence_kernel, dim3(BATCH), dim3(256), 0, stream,
                       SUMM, WC1T, bc1, Wc2, bc2, out);
}